// Round 9
// baseline (290.556 us; speedup 1.0000x reference)
//
#include <hip/hip_runtime.h>
#include <hip/hip_bf16.h>
#include <stdint.h>

typedef unsigned short u16;
typedef __bf16 bf16x8 __attribute__((ext_vector_type(8)));
typedef float f32x4 __attribute__((ext_vector_type(4)));

#define S_LEN 2048
#define BATCH 2
#define NHEADS 16
#define NGROUPS 4
#define DHEAD 128
#define QKV_W 3072   // fused projection width: 2048 q + 1024 kv

__device__ __forceinline__ float bf2f(u16 u) {
  union { uint32_t i; float f; } v; v.i = ((uint32_t)u) << 16; return v.f;
}
__device__ __forceinline__ u16 f2bf(float f) {
  union { float f; uint32_t i; } v; v.f = f;
  uint32_t r = v.i + 0x7FFF + ((v.i >> 16) & 1);
  return (u16)(r >> 16);
}
__device__ __forceinline__ void llds16(const void* g, void* l) {
  __builtin_amdgcn_global_load_lds(
      (const __attribute__((address_space(1))) uint32_t*)g,
      (__attribute__((address_space(3))) uint32_t*)l, 16, 0, 0);
}

// ---------------- RoPE tables: cos/sin (S_LEN x 64) fp32 ----------------
__global__ void rope_tables_k(float* __restrict__ cosT, float* __restrict__ sinT) {
  int i = blockIdx.x * 256 + threadIdx.x;
  int s = i >> 6, j = i & 63;
  float inv = exp2f(-(float)j * 0.20762050593045983f);  // 10000^(-j/64)
  float ang = (float)s * inv;
  float sv, cv;
  sincosf(ang, &sv, &cv);
  cosT[i] = cv; sinT[i] = sv;
}

// ---------------- fp32 -> bf16 elementwise ----------------
__global__ void cvt_f32_bf16(const float* __restrict__ in, u16* __restrict__ out) {
  long i = ((long)blockIdx.x * 256 + threadIdx.x) * 4;
  float4 v = *(const float4*)(in + i);
  ushort4 o;
  o.x = f2bf(v.x); o.y = f2bf(v.y); o.z = f2bf(v.z); o.w = f2bf(v.w);
  *(ushort4*)(out + i) = o;
}

// -------- fp32 (R x C) -> bf16 transpose (C x R) --------
__global__ void transpose_f32_bf16(const float* __restrict__ in, u16* __restrict__ out,
                                   int R, int C) {
  __shared__ u16 tile[32][33];
  int c0 = blockIdx.x * 32, r0 = blockIdx.y * 32;
  int tx = threadIdx.x, ty = threadIdx.y;  // 32 x 8
  for (int i = 0; i < 32; i += 8)
    tile[ty + i][tx] = f2bf(in[(long)(r0 + ty + i) * C + c0 + tx]);
  __syncthreads();
  for (int i = 0; i < 32; i += 8)
    out[(long)(c0 + ty + i) * R + r0 + tx] = tile[tx][ty + i];
}

// ================= shared GEMM helpers =================
#define GFENCE() asm volatile("" ::: "memory")
#define MIDBAR() do { GFENCE(); __builtin_amdgcn_s_barrier(); \
    asm volatile("s_waitcnt lgkmcnt(0)" ::: "memory"); } while (0)
#define ENDBAR() do { GFENCE(); __builtin_amdgcn_s_barrier(); GFENCE(); } while (0)

__device__ __forceinline__ bf16x8 frag_ld(const __bf16* h, int wrow, int kk, int quad) {
  int b = ((wrow & 15) << 6) | (quad << 4);
  b ^= ((wrow >> 3) & 1) << 5;
  int off = ((((wrow >> 4) << 1) | kk) << 10) | b;   // bytes, 16-row blk = 2 KiB
  return *(const bf16x8*)((const char*)h + off);
}

// stage one 64-row x 64-col unit (8 KiB): 1 issue/thread (512 threads)
__device__ __forceinline__ void stage_u64(const u16* __restrict__ g, int K,
                                          __bf16* ldsu, int wv, int lane) {
  int bsrc = (lane << 4) ^ (((lane >> 5) & 1) << 5);
  int r = bsrc >> 6, c = (bsrc & 63) >> 1;
  int cb = (wv & 1) << 5;
  llds16(g + (long)((wv >> 1) * 16 + r) * K + cb + c, ldsu + wv * 512 + lane * 8);
}
__device__ __forceinline__ void stage_half(const u16* __restrict__ g, int K,
                                           __bf16* lhalf, int wv, int lane) {
  stage_u64(g, K, lhalf, wv, lane);
  stage_u64(g + (long)64 * K, K, lhalf + 4096, wv, lane);
}

// ===== 256x192-tile 4-phase GEMM  C = A * B^T  (QKV: N=3072, bf16 out) =====
__global__ __launch_bounds__(512) void gemm_btw(
    const u16* __restrict__ A, const u16* __restrict__ Bt, u16* __restrict__ C,
    int M, int N, int K) {
  __shared__ __align__(16) __bf16 Abuf[2][16384];  // 64 KiB
  __shared__ __align__(16) __bf16 Bbuf[2][12288];  // 48 KiB
  const int tid = threadIdx.x;
  const int wv = tid >> 6, lane = tid & 63;
  const int quad = lane >> 4, l16 = lane & 15;
  const int wr = wv >> 2, wc = wv & 3;

  const int nwg = gridDim.x * gridDim.y;   // 256
  const int orig = blockIdx.y * gridDim.x + blockIdx.x;
  const int swz = (orig & 7) * (nwg >> 3) + (orig >> 3);
  const int bx = swz % gridDim.x, by = swz / gridDim.x;
  const int bm = by * 256, bn = bx * 192;

  const u16* Abase = A + (long)bm * K;
  const u16* Bbase = Bt + (long)bn * K;
  const int NT = K >> 6;

  f32x4 acc[8][3] = {};

#pragma unroll
  for (int t = 0; t < 2; ++t) {
#pragma unroll
    for (int u = 0; u < 4; ++u)
      stage_u64(Abase + (long)u * 64 * K + t * 64, K, &Abuf[t][u * 4096], wv, lane);
#pragma unroll
    for (int u = 0; u < 3; ++u)
      stage_u64(Bbase + (long)u * 64 * K + t * 64, K, &Bbuf[t][u * 4096], wv, lane);
  }
  asm volatile("s_waitcnt vmcnt(7)" ::: "memory");   // K-tile 0 landed
  __builtin_amdgcn_s_barrier();
  GFENCE();

  for (int kt = 0; kt < NT; ++kt) {
    const int buf = kt & 1;
    const __bf16* Ah = &Abuf[buf][wr * 8192];
    const __bf16* Bh = &Bbuf[buf][0];
    const int bn0 = wc * 48;
    const bool pre = (kt + 2 < NT);
    bf16x8 aF[4][2], bF[3][2];

    // ---- P0: read A mh0 + B n0; MFMA m0-3 x n0 ----
#pragma unroll
    for (int m = 0; m < 4; ++m) {
      aF[m][0] = frag_ld(Ah, m * 16 + l16, 0, quad);
      aF[m][1] = frag_ld(Ah, m * 16 + l16, 1, quad);
    }
    bF[0][0] = frag_ld(Bh, bn0 + l16, 0, quad);
    bF[0][1] = frag_ld(Bh, bn0 + l16, 1, quad);
    MIDBAR();
    __builtin_amdgcn_s_setprio(1);
#pragma unroll
    for (int m = 0; m < 4; ++m) {
      acc[m][0] = __builtin_amdgcn_mfma_f32_16x16x32_bf16(aF[m][0], bF[0][0], acc[m][0], 0, 0, 0);
      acc[m][0] = __builtin_amdgcn_mfma_f32_16x16x32_bf16(aF[m][1], bF[0][1], acc[m][0], 0, 0, 0);
    }
    __builtin_amdgcn_s_setprio(0);
    ENDBAR();

    // ---- P1: read B n1,n2; MFMA m0-3 x n1,n2 ----
#pragma unroll
    for (int n = 1; n < 3; ++n) {
      bF[n][0] = frag_ld(Bh, bn0 + n * 16 + l16, 0, quad);
      bF[n][1] = frag_ld(Bh, bn0 + n * 16 + l16, 1, quad);
    }
    MIDBAR();
    __builtin_amdgcn_s_setprio(1);
#pragma unroll
    for (int m = 0; m < 4; ++m)
#pragma unroll
      for (int n = 1; n < 3; ++n) {
        acc[m][n] = __builtin_amdgcn_mfma_f32_16x16x32_bf16(aF[m][0], bF[n][0], acc[m][n], 0, 0, 0);
        acc[m][n] = __builtin_amdgcn_mfma_f32_16x16x32_bf16(aF[m][1], bF[n][1], acc[m][n], 0, 0, 0);
      }
    __builtin_amdgcn_s_setprio(0);
    ENDBAR();

    // ---- P2: read A mh1; stage B(kt+2); MFMA m4-7 x n1,n2 ----
#pragma unroll
    for (int m = 0; m < 4; ++m) {
      aF[m][0] = frag_ld(Ah, 64 + m * 16 + l16, 0, quad);
      aF[m][1] = frag_ld(Ah, 64 + m * 16 + l16, 1, quad);
    }
    if (pre) {
#pragma unroll
      for (int u = 0; u < 3; ++u)
        stage_u64(Bbase + (long)u * 64 * K + (long)(kt + 2) * 64, K,
                  &Bbuf[buf][u * 4096], wv, lane);
    }
    MIDBAR();
    __builtin_amdgcn_s_setprio(1);
#pragma unroll
    for (int m = 0; m < 4; ++m)
#pragma unroll
      for (int n = 1; n < 3; ++n) {
        acc[4 + m][n] = __builtin_amdgcn_mfma_f32_16x16x32_bf16(aF[m][0], bF[n][0], acc[4 + m][n], 0, 0, 0);
        acc[4 + m][n] = __builtin_amdgcn_mfma_f32_16x16x32_bf16(aF[m][1], bF[n][1], acc[4 + m][n], 0, 0, 0);
      }
    __builtin_amdgcn_s_setprio(0);
    ENDBAR();

    // ---- P3: stage A(kt+2); MFMA m4-7 x n0; counted vmcnt ----
    if (pre) {
#pragma unroll
      for (int u = 0; u < 4; ++u)
        stage_u64(Abase + (long)u * 64 * K + (long)(kt + 2) * 64, K,
                  &Abuf[buf][u * 4096], wv, lane);
    }
    MIDBAR();
    __builtin_amdgcn_s_setprio(1);
#pragma unroll
    for (int m = 0; m < 4; ++m) {
      acc[4 + m][0] = __builtin_amdgcn_mfma_f32_16x16x32_bf16(aF[m][0], bF[0][0], acc[4 + m][0], 0, 0, 0);
      acc[4 + m][0] = __builtin_amdgcn_mfma_f32_16x16x32_bf16(aF[m][1], bF[0][1], acc[4 + m][0], 0, 0, 0);
    }
    __builtin_amdgcn_s_setprio(0);
    if (pre) { asm volatile("s_waitcnt vmcnt(7)" ::: "memory"); }
    else     { asm volatile("s_waitcnt vmcnt(0)" ::: "memory"); }
    ENDBAR();
  }

  const long colbase = (long)bn + wc * 48 + l16;
#pragma unroll
  for (int mt = 0; mt < 8; ++mt)
#pragma unroll
    for (int nt = 0; nt < 3; ++nt)
#pragma unroll
      for (int rr = 0; rr < 4; ++rr) {
        long row = bm + wr * 128 + mt * 16 + quad * 4 + rr;
        C[row * N + colbase + nt * 16] = f2bf(acc[mt][nt][rr]);
      }
}

// ==== 256x128-tile 4-phase GEMM  C = A * B^T (dense out, fp32) ====
// R8: converted from 2-phase to the gemm_btw 4-phase schedule (phase
// granularity is the measured lever: 4-phase QKV ~780 TF vs 2-phase ~625).
// P0 {read A mh0 + B n0; MFMA 8}; P1 {read B n1; MFMA 8};
// P2 {read A mh1; stage B(kt+2); MFMA 8}; P3 {stage A(kt+2); MFMA 8;
// vmcnt(6)}.  B last read P1 -> restage P2 safe; A last read P2 -> P3 safe;
// end-of-tile outstanding = 2B + 4A = 6.
__global__ __launch_bounds__(512) void gemm_bt4n(
    const u16* __restrict__ A, const u16* __restrict__ Bt, float* __restrict__ C,
    int M, int N, int K) {
  __shared__ __align__(16) __bf16 Abuf[2][16384];  // 64 KiB
  __shared__ __align__(16) __bf16 Bbuf[2][8192];   // 32 KiB
  const int tid = threadIdx.x;
  const int wv = tid >> 6, lane = tid & 63;
  const int quad = lane >> 4, l16 = lane & 15;
  const int wr = wv >> 2, wc = wv & 3;

  const int nwg = gridDim.x * gridDim.y;   // 256
  const int orig = blockIdx.y * gridDim.x + blockIdx.x;
  const int swz = (orig & 7) * (nwg >> 3) + (orig >> 3);
  const int bx = swz % gridDim.x, by = swz / gridDim.x;
  const int bm = by * 256, bn = bx * 128;

  const u16* Abase = A + (long)bm * K;
  const u16* Bbase = Bt + (long)bn * K;
  const int NT = K >> 6;

  f32x4 acc[8][2] = {};

  // prologue: K-tiles 0 and 1 (A = 4 issues, B = 2 issues each)
#pragma unroll
  for (int t = 0; t < 2; ++t) {
    stage_half(Abase + t * 64, K, &Abuf[t][0], wv, lane);
    stage_half(Abase + (long)128 * K + t * 64, K, &Abuf[t][8192], wv, lane);
    stage_half(Bbase + t * 64, K, &Bbuf[t][0], wv, lane);
  }
  asm volatile("s_waitcnt vmcnt(6)" ::: "memory");   // K-tile 0 landed
  __builtin_amdgcn_s_barrier();
  GFENCE();

  for (int kt = 0; kt < NT; ++kt) {
    const int buf = kt & 1;
    const __bf16* Ah = &Abuf[buf][wr * 8192];
    const __bf16* Bh = &Bbuf[buf][0];
    const int bn0 = wc * 32;
    const bool pre = (kt + 2 < NT);
    bf16x8 aF[4][2], bF[2][2];

    // ---- P0: read A mh0 + B n0; MFMA m0-3 x n0 ----
#pragma unroll
    for (int m = 0; m < 4; ++m) {
      aF[m][0] = frag_ld(Ah, m * 16 + l16, 0, quad);
      aF[m][1] = frag_ld(Ah, m * 16 + l16, 1, quad);
    }
    bF[0][0] = frag_ld(Bh, bn0 + l16, 0, quad);
    bF[0][1] = frag_ld(Bh, bn0 + l16, 1, quad);
    MIDBAR();
    __builtin_amdgcn_s_setprio(1);
#pragma unroll
    for (int m = 0; m < 4; ++m) {
      acc[m][0] = __builtin_amdgcn_mfma_f32_16x16x32_bf16(aF[m][0], bF[0][0], acc[m][0], 0, 0, 0);
      acc[m][0] = __builtin_amdgcn_mfma_f32_16x16x32_bf16(aF[m][1], bF[0][1], acc[m][0], 0, 0, 0);
    }
    __builtin_amdgcn_s_setprio(0);
    ENDBAR();

    // ---- P1: read B n1; MFMA m0-3 x n1 ----
    bF[1][0] = frag_ld(Bh, bn0 + 16 + l16, 0, quad);
    bF[1][1] = frag_ld(Bh, bn0 + 16 + l16, 1, quad);
    MIDBAR();
    __builtin_amdgcn_s_setprio(1);
#pragma unroll
    for (int m = 0; m < 4; ++m) {
      acc[m][1] = __builtin_amdgcn_mfma_f32_16x16x32_bf16(aF[m][0], bF[1][0], acc[m][1], 0, 0, 0);
      acc[m][1] = __builtin_amdgcn_mfma_f32_16x16x32_bf16(aF[m][1], bF[1][1], acc[m][1], 0, 0, 0);
    }
    __builtin_amdgcn_s_setprio(0);
    ENDBAR();

    // ---- P2: read A mh1; stage B(kt+2); MFMA m4-7 x n1 ----
#pragma unroll
    for (int m = 0; m < 4; ++m) {
      aF[m][0] = frag_ld(Ah, 64 + m * 16 + l16, 0, quad);
      aF[m][1] = frag_ld(Ah, 64 + m * 16 + l16, 1, quad);
    }
    if (pre) {
      stage_half(Bbase + (long)(kt + 2) * 64, K, &Bbuf[buf][0], wv, lane);
    }
    MIDBAR();
    __builtin_amdgcn_s_setprio(1);
#pragma unroll
    for (int m = 0; m < 4; ++m) {
      acc[4 + m][1] = __builtin_amdgcn_mfma_f32_16x16x32_bf16(aF[m][0], bF[1][0], acc[4 + m][1], 0, 0, 0);
      acc[4 + m][1] = __builtin_amdgcn_mfma_f32_16x16x32_bf16(aF[m][1], bF[1][1], acc[4 + m][1], 0, 0, 0);
    }
    __builtin_amdgcn_s_setprio(0);
    ENDBAR();

    // ---- P3: stage A(kt+2); MFMA m4-7 x n0; counted vmcnt ----
    if (pre) {
      const u16* p = Abase + (long)(kt + 2) * 64;
      stage_half(p, K, &Abuf[buf][0], wv, lane);
      stage_half(p + (long)128 * K, K, &Abuf[buf][8192], wv, lane);
    }
    MIDBAR();
    __builtin_amdgcn_s_setprio(1);
#pragma unroll
    for (int m = 0; m < 4; ++m) {
      acc[4 + m][0] = __builtin_amdgcn_mfma_f32_16x16x32_bf16(aF[m][0], bF[0][0], acc[4 + m][0], 0, 0, 0);
      acc[4 + m][0] = __builtin_amdgcn_mfma_f32_16x16x32_bf16(aF[m][1], bF[0][1], acc[4 + m][0], 0, 0, 0);
    }
    __builtin_amdgcn_s_setprio(0);
    if (pre) { asm volatile("s_waitcnt vmcnt(6)" ::: "memory"); }
    else     { asm volatile("s_waitcnt vmcnt(0)" ::: "memory"); }
    ENDBAR();
  }

  const long colbase = (long)bn + wc * 32 + l16;
#pragma unroll
  for (int mt = 0; mt < 8; ++mt)
#pragma unroll
    for (int nt = 0; nt < 2; ++nt)
#pragma unroll
      for (int rr = 0; rr < 4; ++rr) {
        long row = bm + wr * 128 + mt * 16 + quad * 4 + rr;
        C[row * N + colbase + nt * 16] = acc[mt][nt][rr];
      }
}

// ---- RoPE on K: qkv cols [2048,2560) -> Kb (B,4,S,128) ----
__global__ void rope_k_k(const u16* __restrict__ qkv, u16* __restrict__ Kb,
                         const float* __restrict__ cosT, const float* __restrict__ sinT) {
  long i = (long)blockIdx.x * 256 + threadIdx.x;   // < B*S*4*64
  int j = i & 63;
  long rest = i >> 6;
  int g = rest & 3;
  long bs = rest >> 2;
  int s = bs & (S_LEN - 1);
  int b = (int)(bs >> 11);
  long src = bs * QKV_W + 2048 + g * 128 + j;
  float x1 = bf2f(qkv[src]), x2 = bf2f(qkv[src + 64]);
  float c = cosT[s * 64 + j], sn = sinT[s * 64 + j];
  long dst = ((long)(b * NGROUPS + g) * S_LEN + s) * DHEAD + j;
  Kb[dst] = f2bf(x1 * c - x2 * sn);
  Kb[dst + 64] = f2bf(x2 * c + x1 * sn);
}

// ---- V transpose: qkv cols [2560,3072) -> Vt (B,4,128,S) ----
__global__ void v_trans_k(const u16* __restrict__ qkv, u16* __restrict__ Vt) {
  __shared__ u16 tile[32][33];
  int s0 = blockIdx.x * 32, d0 = blockIdx.y * 32;
  int bg = blockIdx.z;
  int b = bg >> 2, g = bg & 3;
  int tx = threadIdx.x, ty = threadIdx.y;
  for (int i = 0; i < 32; i += 8) {
    long s = s0 + ty + i;
    tile[ty + i][tx] = qkv[((long)b * S_LEN + s) * QKV_W + 2560 + g * 128 + d0 + tx];
  }
  __syncthreads();
  for (int i = 0; i < 32; i += 8) {
    int d = d0 + ty + i;
    Vt[((long)(b * NGROUPS + g) * DHEAD + d) * S_LEN + s0 + tx] = tile[tx][ty + i];
  }
}

// ---- Flash attention v13: v11 structure (best measured) + scr-132 fix ----
// R8 post-mortem: v12's 3-deep counted-vmcnt pipeline REGRESSED (69.2->73.5);
// the per-chunk drain was already hidden (staging issued a full chunk ahead).
// Revert to v11's 2-buffer + __syncthreads schedule; keep only the proven
// epilogue fix (scr row stride 132 floats -> bank conflicts 524K -> 0).
__global__ __launch_bounds__(512, 2) void attn_k13(
    const u16* __restrict__ Q,   // qkv (B,S,3072), cols [0,2048) PRE-rope
    const u16* __restrict__ Kb,  // (B,4,S,128)  post-rope
    const u16* __restrict__ Vt,  // (B,4,128,S)
    const float* __restrict__ cosT, const float* __restrict__ sinT,
    u16* __restrict__ ctx) {     // (B,S,16,128)
  __shared__ __align__(16) char smem[82432];
  __bf16* Ks   = (__bf16*)smem;             // [2][64*128]  32 KB
  __bf16* Vts  = (__bf16*)(smem + 32768);   // [2][128*64]  32 KB
  __bf16* Ps   = (__bf16*)(smem + 65536);   // [4 rg][32*64] 16 KB
  float*  Psum = (float*)(smem + 81920);    // [128]        512 B
  float*  scr  = (float*)smem;              // epilogue overlay (66 KB @132)

  const int h = blockIdx.y, b = blockIdx.z, g = h >> 2;
  const int tx = blockIdx.x;                // 0..7
  const int tid = threadIdx.x, wv = tid >> 6, lane = tid & 63;
  const int quad = lane >> 4, l16 = lane & 15;
  const int rg = wv & 3;        // row-group within tile (32 rows)
  const int kh = wv >> 2;       // key half of each chunk
  const float SCALE = 0.08838834764831845f;

  const long kbase = (long)(b * NGROUPS + g) * S_LEN * DHEAD;
  const long vbase = (long)(b * NGROUPS + g) * DHEAD * S_LEN;

  const int krow_off = lane >> 4;
  const int vrow_off = lane >> 3;

  const __bf16 oneb = (__bf16)((l16 == 0) ? 1.0f : 0.0f);
  const bf16x8 bones = {oneb, oneb, oneb, oneb, oneb, oneb, oneb, oneb};

  __bf16* Prg = Ps + rg * 2048;  // row-group's 32x64 P tile (shared by pair)

  for (int pass = 0; pass < 2; ++pass) {
    const int tile = pass ? (15 - tx) : tx;
    const int q0 = tile * 128;
    const int nch = 2 * (tile + 1);   // 64-key chunks

    // Q fragments with fused RoPE: rows q0 + rg*32 + m*16 + l16
    bf16x8 aq[2][4];
#pragma unroll
    for (int m = 0; m < 2; ++m) {
      const int srow = q0 + rg * 32 + m * 16 + l16;
      const u16* qp = Q + (long)(b * S_LEN + srow) * QKV_W + h * DHEAD + quad * 8;
      bf16x8 raw[4];
#pragma unroll
      for (int ds = 0; ds < 4; ++ds)
        raw[ds] = *(const bf16x8*)(qp + ds * 32);
      const float* cb = cosT + srow * 64 + quad * 8;
      const float* sb = sinT + srow * 64 + quad * 8;
#pragma unroll
      for (int ds = 0; ds < 2; ++ds)
#pragma unroll
        for (int e = 0; e < 8; ++e) {
          float c = cb[ds * 32 + e], s = sb[ds * 32 + e];
          float lo = (float)raw[ds][e], hi = (float)raw[ds + 2][e];
          aq[m][ds][e]     = (__bf16)(lo * c - hi * s);
          aq[m][ds + 2][e] = (__bf16)(hi * c + lo * s);
        }
    }

    // prologue: stage K/V chunk 0 into buffer 0 (8 waves, 2 issues each)
#pragma unroll
    for (int i = 0; i < 2; ++i) {
      int r0 = wv * 8 + i * 4;
      int row = r0 + krow_off;
      int c = l16 ^ (row & 15);
      llds16(Kb + kbase + (long)row * DHEAD + c * 8, &Ks[r0 * 128 + lane * 8]);
    }
#pragma unroll
    for (int i = 0; i < 2; ++i) {
      int d0 = wv * 16 + i * 8;
      int row = d0 + vrow_off;
      int c = (lane & 7) ^ (row & 7);
      llds16(Vt + vbase + (long)row * S_LEN + c * 8, &Vts[d0 * 64 + lane * 8]);
    }
    __syncthreads();

    f32x4 Oacc[2][8] = {};
    f32x4 Osum[2] = {};
    const int rmin = q0 + rg * 32;   // wave's lowest q-row

    for (int kc = 0; kc < nch; ++kc) {
      const int cur = kc & 1;
      if (kc + 1 < nch) {
        const int nxt = cur ^ 1;
#pragma unroll
        for (int i = 0; i < 2; ++i) {
          int r0 = wv * 8 + i * 4;
          int row = r0 + krow_off;
          int c = l16 ^ (row & 15);
          llds16(Kb + kbase + (long)((kc + 1) * 64 + row) * DHEAD + c * 8,
                 &Ks[nxt * 8192 + r0 * 128 + lane * 8]);
        }
#pragma unroll
        for (int i = 0; i < 2; ++i) {
          int d0 = wv * 16 + i * 8;
          int row = d0 + vrow_off;
          int c = (lane & 7) ^ (row & 7);
          llds16(Vt + vbase + (long)row * S_LEN + (kc + 1) * 64 + c * 8,
                 &Vts[nxt * 8192 + d0 * 64 + lane * 8]);
        }
      }

      const int kb0 = kc * 64 + kh * 32;            // wave's key base
      const bool skip = kb0 > (rmin + 31);          // fully above diagonal
      if (!skip) {
        // QK^T: 32q x 32k per wave (16 MFMA, 8 K-frag reads)
        f32x4 sacc[2][2] = {};
        __builtin_amdgcn_s_setprio(1);
#pragma unroll
        for (int ds = 0; ds < 4; ++ds) {
          int pos0 = ((ds * 4 + quad) ^ l16) * 8;
#pragma unroll
          for (int nt = 0; nt < 2; ++nt) {
            bf16x8 bk = *(const bf16x8*)&Ks[cur * 8192 + (kh * 32 + nt * 16 + l16) * 128 + pos0];
            sacc[0][nt] = __builtin_amdgcn_mfma_f32_16x16x32_bf16(aq[0][ds], bk, sacc[0][nt], 0, 0, 0);
            sacc[1][nt] = __builtin_amdgcn_mfma_f32_16x16x32_bf16(aq[1][ds], bk, sacc[1][nt], 0, 0, 0);
          }
        }
        __builtin_amdgcn_s_setprio(0);

        // softmax -> P tile: granule gq = kh*4 + local, pos = gq ^ (row&7)
        const bool need_mask = (kb0 + 31) > rmin;
        if (need_mask) {
#pragma unroll
          for (int m = 0; m < 2; ++m)
#pragma unroll
            for (int nt = 0; nt < 2; ++nt)
#pragma unroll
              for (int r = 0; r < 4; ++r) {
                int qrow = rmin + m * 16 + quad * 4 + r;
                int key = kb0 + nt * 16 + l16;
                float p = (key <= qrow) ? __expf(sacc[m][nt][r] * SCALE) : 0.f;
                int row = m * 16 + quad * 4 + r;
                int gq = kh * 4 + nt * 2 + (l16 >> 3);
                int pos = gq ^ (row & 7);
                Prg[row * 64 + pos * 8 + (l16 & 7)] = (__bf16)p;
              }
        } else {
#pragma unroll
          for (int m = 0; m < 2; ++m)
#pragma unroll
            for (int nt = 0; nt < 2; ++nt)
#pragma unroll
              for (int r = 0; r < 4; ++r) {
                float p = __expf(sacc[m][nt][r] * SCALE);
                int row = m * 16 + quad * 4 + r;
                int gq = kh * 4 + nt * 2 + (l16 >> 3);
                int pos = gq ^ (row & 7);
                Prg[row * 64 + pos * 8 + (l16 & 7)] = (__bf16)p;
              }
        }

        // PV over wave's 32 keys (K=32: one MFMA step), 8 V-frag reads
        bf16x8 ap[2];
#pragma unroll
        for (int m = 0; m < 2; ++m) {
          int pos = (kh * 4 + quad) ^ (l16 & 7);
          ap[m] = *(const bf16x8*)&Prg[(m * 16 + l16) * 64 + pos * 8];
        }
        __builtin_amdgcn_s_setprio(1);
#pragma unroll
        for (int nt = 0; nt < 8; ++nt) {
          int pos = (((kh << 2) | quad) ^ (l16 & 7)) * 8;
          bf16x8 bv = *(const bf16x8*)&Vts[cur * 8192 + (nt * 16 + l16) * 64 + pos];
          Oacc[0][nt] = __builtin_amdgcn_mfma_f32_16x16x32_bf16(ap[0], bv, Oacc[0][nt], 0, 0, 0);
          Oacc[1][nt] = __builtin_amdgcn_mfma_f32_16x16x32_bf16(ap[1], bv, Oacc[1][nt], 0, 0, 0);
        }
#pragma unroll
        for (int m = 0; m < 2; ++m)
          Osum[m] = __builtin_amdgcn_mfma_f32_16x16x32_bf16(ap[m], bones, Osum[m], 0, 0, 0);
        __builtin_amdgcn_s_setprio(0);
      }

      __syncthreads();
    }

    // ---- combine wave pair (kh=1 partial added into kh=0) ----
    if (kh == 1) {
      float* s = scr + rg * 4224;   // 32 rows x 132-stride f32 (2-way banks)
#pragma unroll
      for (int m = 0; m < 2; ++m)
#pragma unroll
        for (int nt = 0; nt < 8; ++nt)
#pragma unroll
          for (int r = 0; r < 4; ++r)
            s[(m * 16 + quad * 4 + r) * 132 + nt * 16 + l16] = Oacc[m][nt][r];
      if (l16 == 0) {
#pragma unroll
        for (int m = 0; m < 2; ++m)
#pragma unroll
          for (int r = 0; r < 4; ++r)
            Psum[rg * 32 + m * 16 + quad * 4 + r] = Osum[m][r];
      }
    }
    __syncthreads();
    if (kh == 0) {
      float* s = scr + rg * 4224;
#pragma unroll
      for (int m = 0; m < 2; ++m) {
        float lsum[4];
#pragma unroll
        for (int r = 0; r < 4; ++r)
          lsum[r] = __shfl(Osum[m][r], quad << 4, 64) +
                    Psum[rg * 32 + m * 16 + quad * 4 + r];
        const long obase = ((long)(b * S_LEN + q0 + rg * 32 + m * 16) * NHEADS + h) * DHEAD;
#pragma unroll
        for (int nt = 0; nt < 8; ++nt)
#pragma unroll
          for (int r = 0; r < 4; ++r) {
            int lrow = quad * 4 + r;
            float v = Oacc[m][nt][r] + s[(m * 16 + lrow) * 132 + nt * 16 + l16];
            ctx[obase + (long)lrow * NHEADS * DHEAD + nt * 16 + l16] = f2bf(v / lsum[r]);
          }
      }
    }
    __syncthreads();   // scratch free before next pass restages K/V
  }
}

extern "C" void kernel_launch(void* const* d_in, const int* in_sizes, int n_in,
                              void* d_out, int out_size, void* d_ws, size_t ws_size,
                              hipStream_t stream) {
  const float* x   = (const float*)d_in[0];   // (B,S,2048) fp32
  const float* wq  = (const float*)d_in[1];   // (2048, 2048) fp32
  const float* wkv = (const float*)d_in[2];   // (2048, 1024) fp32
  const float* wd  = (const float*)d_in[3];   // (2048, 2048) fp32
  float* out = (float*)d_out;                 // (B,S,2048) fp32

  char* ws = (char*)d_ws;
  float* cosT  = (float*)(ws + 0);             //   524288 B
  float* sinT  = (float*)(ws + 524288);        //   524288 B
  u16* wqkvT = (u16*)(ws + 1048576);           // 12582912 B (3072 x 2048 bf16)
  u16* wdT   = (u16*)(ws + 13631488);          //  8388608 B (2048 x 2048 bf16)
  u16* xb    = (u16*)(ws + 22020096);          // 16777216 B (B*S, 2048) bf16
  u16* qkv   = (u16*)(ws + 38797312);          // 25165824 B (B*S, 3072) bf16
  u16* Kb    = (u16*)(ws + 63963136);          //  4194304 B (B,4,S,128) bf16
  u16* Vt    = (u16*)(ws + 68157440);          //  4194304 B (B,4,128,S) bf16
  u16* ctx   = (u16*)(ws + 72351744);          // 16777216 B (B,S,16,128) bf16
                                               // total 89128960 B

  rope_tables_k<<<512, 256, 0, stream>>>(cosT, sinT);
  cvt_f32_bf16<<<8192, 256, 0, stream>>>(x, xb);
  transpose_f32_bf16<<<dim3(64, 64), dim3(32, 8), 0, stream>>>(wq, wqkvT, 2048, 2048);
  transpose_f32_bf16<<<dim3(32, 64), dim3(32, 8), 0, stream>>>(wkv, wqkvT + (long)2048 * 2048, 2048, 1024);
  transpose_f32_bf16<<<dim3(64, 64), dim3(32, 8), 0, stream>>>(wd, wdT, 2048, 2048);

  // fused QKV projection: (B*S,2048) x (3072,2048)^T -> (B*S,3072)
  gemm_btw<<<dim3(16, 16), 512, 0, stream>>>(xb, wqkvT, qkv, 4096, 3072, 2048);

  rope_k_k<<<4096, 256, 0, stream>>>(qkv, Kb, cosT, sinT);
  v_trans_k<<<dim3(64, 4, 8), dim3(32, 8), 0, stream>>>(qkv, Vt);

  attn_k13<<<dim3(8, 16, 2), 512, 0, stream>>>(qkv, Kb, Vt, cosT, sinT, ctx);

  // dense out: (B*S,2048) x (2048,2048)^T -> (B*S,2048), 4-phase, 256 blocks
  gemm_bt4n<<<dim3(16, 16), 512, 0, stream>>>(ctx, wdT, out, 4096, 2048, 2048);
}

// Round 10
// 282.286 us; speedup vs baseline: 1.0293x; 1.0293x over previous
//
#include <hip/hip_runtime.h>
#include <hip/hip_bf16.h>
#include <stdint.h>

typedef unsigned short u16;
typedef __bf16 bf16x8 __attribute__((ext_vector_type(8)));
typedef float f32x4 __attribute__((ext_vector_type(4)));

#define S_LEN 2048
#define BATCH 2
#define NHEADS 16
#define NGROUPS 4
#define DHEAD 128
#define QKV_W 3072   // fused projection width: 2048 q + 1024 kv

__device__ __forceinline__ float bf2f(u16 u) {
  union { uint32_t i; float f; } v; v.i = ((uint32_t)u) << 16; return v.f;
}
__device__ __forceinline__ u16 f2bf(float f) {
  union { float f; uint32_t i; } v; v.f = f;
  uint32_t r = v.i + 0x7FFF + ((v.i >> 16) & 1);
  return (u16)(r >> 16);
}
__device__ __forceinline__ void llds16(const void* g, void* l) {
  __builtin_amdgcn_global_load_lds(
      (const __attribute__((address_space(1))) uint32_t*)g,
      (__attribute__((address_space(3))) uint32_t*)l, 16, 0, 0);
}

// ---------------- RoPE tables: cos/sin (S_LEN x 64) fp32 ----------------
__global__ void rope_tables_k(float* __restrict__ cosT, float* __restrict__ sinT) {
  int i = blockIdx.x * 256 + threadIdx.x;
  int s = i >> 6, j = i & 63;
  float inv = exp2f(-(float)j * 0.20762050593045983f);  // 10000^(-j/64)
  float ang = (float)s * inv;
  float sv, cv;
  sincosf(ang, &sv, &cv);
  cosT[i] = cv; sinT[i] = sv;
}

// ---------------- fp32 -> bf16 elementwise ----------------
__global__ void cvt_f32_bf16(const float* __restrict__ in, u16* __restrict__ out) {
  long i = ((long)blockIdx.x * 256 + threadIdx.x) * 4;
  float4 v = *(const float4*)(in + i);
  ushort4 o;
  o.x = f2bf(v.x); o.y = f2bf(v.y); o.z = f2bf(v.z); o.w = f2bf(v.w);
  *(ushort4*)(out + i) = o;
}

// ---- merged weight transposes: z=0 wq, z=1 wkv (bx<32), z=2 wd ----
__global__ void transpose3_k(const float* __restrict__ wq,
                             const float* __restrict__ wkv,
                             const float* __restrict__ wd,
                             u16* __restrict__ wqkvT, u16* __restrict__ wdT) {
  __shared__ u16 tile[32][33];
  const int z = blockIdx.z;
  const float* in; u16* out; int R, C;
  if (z == 0)      { in = wq;  out = wqkvT;                       R = 2048; C = 2048; }
  else if (z == 1) { if (blockIdx.x >= 32) return;
                     in = wkv; out = wqkvT + (long)2048 * 2048;   R = 2048; C = 1024; }
  else             { in = wd;  out = wdT;                         R = 2048; C = 2048; }
  int c0 = blockIdx.x * 32, r0 = blockIdx.y * 32;
  int tx = threadIdx.x, ty = threadIdx.y;  // 32 x 8
  for (int i = 0; i < 32; i += 8)
    tile[ty + i][tx] = f2bf(in[(long)(r0 + ty + i) * C + c0 + tx]);
  __syncthreads();
  for (int i = 0; i < 32; i += 8)
    out[(long)(c0 + ty + i) * R + r0 + tx] = tile[tx][ty + i];
}

// ================= shared GEMM helpers =================
#define GFENCE() asm volatile("" ::: "memory")
#define MIDBAR() do { GFENCE(); __builtin_amdgcn_s_barrier(); \
    asm volatile("s_waitcnt lgkmcnt(0)" ::: "memory"); } while (0)
#define ENDBAR() do { GFENCE(); __builtin_amdgcn_s_barrier(); GFENCE(); } while (0)

__device__ __forceinline__ bf16x8 frag_ld(const __bf16* h, int wrow, int kk, int quad) {
  int b = ((wrow & 15) << 6) | (quad << 4);
  b ^= ((wrow >> 3) & 1) << 5;
  int off = ((((wrow >> 4) << 1) | kk) << 10) | b;   // bytes, 16-row blk = 2 KiB
  return *(const bf16x8*)((const char*)h + off);
}

// stage one 64-row x 64-col unit (8 KiB): 1 issue/thread (512 threads)
__device__ __forceinline__ void stage_u64(const u16* __restrict__ g, int K,
                                          __bf16* ldsu, int wv, int lane) {
  int bsrc = (lane << 4) ^ (((lane >> 5) & 1) << 5);
  int r = bsrc >> 6, c = (bsrc & 63) >> 1;
  int cb = (wv & 1) << 5;
  llds16(g + (long)((wv >> 1) * 16 + r) * K + cb + c, ldsu + wv * 512 + lane * 8);
}
__device__ __forceinline__ void stage_half(const u16* __restrict__ g, int K,
                                           __bf16* lhalf, int wv, int lane) {
  stage_u64(g, K, lhalf, wv, lane);
  stage_u64(g + (long)64 * K, K, lhalf + 4096, wv, lane);
}

// ===== 256x192-tile 4-phase GEMM  C = A * B^T  (QKV: N=3072, bf16 out) =====
__global__ __launch_bounds__(512) void gemm_btw(
    const u16* __restrict__ A, const u16* __restrict__ Bt, u16* __restrict__ C,
    int M, int N, int K) {
  __shared__ __align__(16) __bf16 Abuf[2][16384];  // 64 KiB
  __shared__ __align__(16) __bf16 Bbuf[2][12288];  // 48 KiB
  const int tid = threadIdx.x;
  const int wv = tid >> 6, lane = tid & 63;
  const int quad = lane >> 4, l16 = lane & 15;
  const int wr = wv >> 2, wc = wv & 3;

  const int nwg = gridDim.x * gridDim.y;   // 256
  const int orig = blockIdx.y * gridDim.x + blockIdx.x;
  const int swz = (orig & 7) * (nwg >> 3) + (orig >> 3);
  const int bx = swz % gridDim.x, by = swz / gridDim.x;
  const int bm = by * 256, bn = bx * 192;

  const u16* Abase = A + (long)bm * K;
  const u16* Bbase = Bt + (long)bn * K;
  const int NT = K >> 6;

  f32x4 acc[8][3] = {};

#pragma unroll
  for (int t = 0; t < 2; ++t) {
#pragma unroll
    for (int u = 0; u < 4; ++u)
      stage_u64(Abase + (long)u * 64 * K + t * 64, K, &Abuf[t][u * 4096], wv, lane);
#pragma unroll
    for (int u = 0; u < 3; ++u)
      stage_u64(Bbase + (long)u * 64 * K + t * 64, K, &Bbuf[t][u * 4096], wv, lane);
  }
  asm volatile("s_waitcnt vmcnt(7)" ::: "memory");   // K-tile 0 landed
  __builtin_amdgcn_s_barrier();
  GFENCE();

  for (int kt = 0; kt < NT; ++kt) {
    const int buf = kt & 1;
    const __bf16* Ah = &Abuf[buf][wr * 8192];
    const __bf16* Bh = &Bbuf[buf][0];
    const int bn0 = wc * 48;
    const bool pre = (kt + 2 < NT);
    bf16x8 aF[4][2], bF[3][2];

    // ---- P0: read A mh0 + B n0; MFMA m0-3 x n0 ----
#pragma unroll
    for (int m = 0; m < 4; ++m) {
      aF[m][0] = frag_ld(Ah, m * 16 + l16, 0, quad);
      aF[m][1] = frag_ld(Ah, m * 16 + l16, 1, quad);
    }
    bF[0][0] = frag_ld(Bh, bn0 + l16, 0, quad);
    bF[0][1] = frag_ld(Bh, bn0 + l16, 1, quad);
    MIDBAR();
    __builtin_amdgcn_s_setprio(1);
#pragma unroll
    for (int m = 0; m < 4; ++m) {
      acc[m][0] = __builtin_amdgcn_mfma_f32_16x16x32_bf16(aF[m][0], bF[0][0], acc[m][0], 0, 0, 0);
      acc[m][0] = __builtin_amdgcn_mfma_f32_16x16x32_bf16(aF[m][1], bF[0][1], acc[m][0], 0, 0, 0);
    }
    __builtin_amdgcn_s_setprio(0);
    ENDBAR();

    // ---- P1: read B n1,n2; MFMA m0-3 x n1,n2 ----
#pragma unroll
    for (int n = 1; n < 3; ++n) {
      bF[n][0] = frag_ld(Bh, bn0 + n * 16 + l16, 0, quad);
      bF[n][1] = frag_ld(Bh, bn0 + n * 16 + l16, 1, quad);
    }
    MIDBAR();
    __builtin_amdgcn_s_setprio(1);
#pragma unroll
    for (int m = 0; m < 4; ++m)
#pragma unroll
      for (int n = 1; n < 3; ++n) {
        acc[m][n] = __builtin_amdgcn_mfma_f32_16x16x32_bf16(aF[m][0], bF[n][0], acc[m][n], 0, 0, 0);
        acc[m][n] = __builtin_amdgcn_mfma_f32_16x16x32_bf16(aF[m][1], bF[n][1], acc[m][n], 0, 0, 0);
      }
    __builtin_amdgcn_s_setprio(0);
    ENDBAR();

    // ---- P2: read A mh1; stage B(kt+2); MFMA m4-7 x n1,n2 ----
#pragma unroll
    for (int m = 0; m < 4; ++m) {
      aF[m][0] = frag_ld(Ah, 64 + m * 16 + l16, 0, quad);
      aF[m][1] = frag_ld(Ah, 64 + m * 16 + l16, 1, quad);
    }
    if (pre) {
#pragma unroll
      for (int u = 0; u < 3; ++u)
        stage_u64(Bbase + (long)u * 64 * K + (long)(kt + 2) * 64, K,
                  &Bbuf[buf][u * 4096], wv, lane);
    }
    MIDBAR();
    __builtin_amdgcn_s_setprio(1);
#pragma unroll
    for (int m = 0; m < 4; ++m)
#pragma unroll
      for (int n = 1; n < 3; ++n) {
        acc[4 + m][n] = __builtin_amdgcn_mfma_f32_16x16x32_bf16(aF[m][0], bF[n][0], acc[4 + m][n], 0, 0, 0);
        acc[4 + m][n] = __builtin_amdgcn_mfma_f32_16x16x32_bf16(aF[m][1], bF[n][1], acc[4 + m][n], 0, 0, 0);
      }
    __builtin_amdgcn_s_setprio(0);
    ENDBAR();

    // ---- P3: stage A(kt+2); MFMA m4-7 x n0; counted vmcnt ----
    if (pre) {
#pragma unroll
      for (int u = 0; u < 4; ++u)
        stage_u64(Abase + (long)u * 64 * K + (long)(kt + 2) * 64, K,
                  &Abuf[buf][u * 4096], wv, lane);
    }
    MIDBAR();
    __builtin_amdgcn_s_setprio(1);
#pragma unroll
    for (int m = 0; m < 4; ++m) {
      acc[4 + m][0] = __builtin_amdgcn_mfma_f32_16x16x32_bf16(aF[m][0], bF[0][0], acc[4 + m][0], 0, 0, 0);
      acc[4 + m][0] = __builtin_amdgcn_mfma_f32_16x16x32_bf16(aF[m][1], bF[0][1], acc[4 + m][0], 0, 0, 0);
    }
    __builtin_amdgcn_s_setprio(0);
    if (pre) { asm volatile("s_waitcnt vmcnt(7)" ::: "memory"); }
    else     { asm volatile("s_waitcnt vmcnt(0)" ::: "memory"); }
    ENDBAR();
  }

  const long colbase = (long)bn + wc * 48 + l16;
#pragma unroll
  for (int mt = 0; mt < 8; ++mt)
#pragma unroll
    for (int nt = 0; nt < 3; ++nt)
#pragma unroll
      for (int rr = 0; rr < 4; ++rr) {
        long row = bm + wr * 128 + mt * 16 + quad * 4 + rr;
        C[row * N + colbase + nt * 16] = f2bf(acc[mt][nt][rr]);
      }
}

// ======== 256x128-tile 2-phase GEMM  C = A * B^T (dense out, fp32) ========
// R9: reverted from 4-phase (R8 experiment regressed ~5 us: only 8 MFMA per
// barrier pair vs 16 here; barrier overhead dominated).  This is the R7
// version that measured best.
__global__ __launch_bounds__(512) void gemm_bt8n(
    const u16* __restrict__ A, const u16* __restrict__ Bt, float* __restrict__ C,
    int M, int N, int K) {
  __shared__ __align__(16) __bf16 Abuf[2][16384];  // 64 KiB
  __shared__ __align__(16) __bf16 Bbuf[2][8192];   // 32 KiB
  const int tid = threadIdx.x;
  const int wv = tid >> 6, lane = tid & 63;
  const int quad = lane >> 4, l16 = lane & 15;
  const int wr = wv >> 2, wc = wv & 3;

  const int nwg = gridDim.x * gridDim.y;   // 256
  const int orig = blockIdx.y * gridDim.x + blockIdx.x;
  const int swz = (orig & 7) * (nwg >> 3) + (orig >> 3);
  const int bx = swz % gridDim.x, by = swz / gridDim.x;
  const int bm = by * 256, bn = bx * 128;

  const u16* Abase = A + (long)bm * K;
  const u16* Bbase = Bt + (long)bn * K;
  const int NT = K >> 6;

  f32x4 acc[8][2] = {};

  stage_half(Abase, K, &Abuf[0][0], wv, lane);
  stage_half(Abase + (long)128 * K, K, &Abuf[0][8192], wv, lane);
  stage_half(Bbase, K, &Bbuf[0][0], wv, lane);
  stage_half(Abase + 64, K, &Abuf[1][0], wv, lane);
  stage_half(Abase + (long)128 * K + 64, K, &Abuf[1][8192], wv, lane);
  stage_half(Bbase + 64, K, &Bbuf[1][0], wv, lane);
  asm volatile("s_waitcnt vmcnt(0)" ::: "memory");
  __builtin_amdgcn_s_barrier();
  GFENCE();

  for (int kt = 0; kt < NT; ++kt) {
    const int buf = kt & 1;
    const __bf16* Ah = &Abuf[buf][wr * 8192];
    const __bf16* Bh = &Bbuf[buf][0];
    bf16x8 aF[4][2], bF[2][2];

#pragma unroll
    for (int m = 0; m < 4; ++m) {
      aF[m][0] = frag_ld(Ah, m * 16 + l16, 0, quad);
      aF[m][1] = frag_ld(Ah, m * 16 + l16, 1, quad);
    }
#pragma unroll
    for (int n = 0; n < 2; ++n) {
      bF[n][0] = frag_ld(Bh, wc * 32 + n * 16 + l16, 0, quad);
      bF[n][1] = frag_ld(Bh, wc * 32 + n * 16 + l16, 1, quad);
    }
    if (kt >= 1 && kt + 1 < NT) {
      const u16* p = Abase + (long)(kt + 1) * 64;
      stage_half(p, K, &Abuf[(kt + 1) & 1][0], wv, lane);
      stage_half(p + (long)128 * K, K, &Abuf[(kt + 1) & 1][8192], wv, lane);
    }
    MIDBAR();
    __builtin_amdgcn_s_setprio(1);
#pragma unroll
    for (int m = 0; m < 4; ++m)
#pragma unroll
      for (int n = 0; n < 2; ++n) {
        acc[m][n] = __builtin_amdgcn_mfma_f32_16x16x32_bf16(aF[m][0], bF[n][0], acc[m][n], 0, 0, 0);
        acc[m][n] = __builtin_amdgcn_mfma_f32_16x16x32_bf16(aF[m][1], bF[n][1], acc[m][n], 0, 0, 0);
      }
    __builtin_amdgcn_s_setprio(0);
    ENDBAR();

#pragma unroll
    for (int m = 0; m < 4; ++m) {
      aF[m][0] = frag_ld(Ah, 64 + m * 16 + l16, 0, quad);
      aF[m][1] = frag_ld(Ah, 64 + m * 16 + l16, 1, quad);
    }
    if (kt + 2 < NT) {
      stage_half(Bbase + (long)(kt + 2) * 64, K, &Bbuf[buf][0], wv, lane);
    }
    MIDBAR();
    __builtin_amdgcn_s_setprio(1);
#pragma unroll
    for (int m = 0; m < 4; ++m)
#pragma unroll
      for (int n = 0; n < 2; ++n) {
        acc[4 + m][n] = __builtin_amdgcn_mfma_f32_16x16x32_bf16(aF[m][0], bF[n][0], acc[4 + m][n], 0, 0, 0);
        acc[4 + m][n] = __builtin_amdgcn_mfma_f32_16x16x32_bf16(aF[m][1], bF[n][1], acc[4 + m][n], 0, 0, 0);
      }
    __builtin_amdgcn_s_setprio(0);
    if (kt + 2 < NT) { asm volatile("s_waitcnt vmcnt(2)" ::: "memory"); }
    else             { asm volatile("s_waitcnt vmcnt(0)" ::: "memory"); }
    ENDBAR();
  }

  const long colbase = (long)bn + wc * 32 + l16;
#pragma unroll
  for (int mt = 0; mt < 8; ++mt)
#pragma unroll
    for (int nt = 0; nt < 2; ++nt)
#pragma unroll
      for (int rr = 0; rr < 4; ++rr) {
        long row = bm + wr * 128 + mt * 16 + quad * 4 + rr;
        C[row * N + colbase + nt * 16] = acc[mt][nt][rr];
      }
}

// ---- merged KV prep: blocks [0,4096) = RoPE-K, [4096,6144) = V transpose ----
__global__ void kv_prep_k(const u16* __restrict__ qkv, u16* __restrict__ Kb,
                          u16* __restrict__ Vt,
                          const float* __restrict__ cosT,
                          const float* __restrict__ sinT) {
  __shared__ u16 tile[32][33];
  const int bx = blockIdx.x;
  if (bx < 4096) {
    // RoPE on K: qkv cols [2048,2560) -> Kb (B,4,S,128)
    long i = (long)bx * 256 + threadIdx.x;   // < B*S*4*64
    int j = i & 63;
    long rest = i >> 6;
    int g = rest & 3;
    long bs = rest >> 2;
    int s = bs & (S_LEN - 1);
    int b = (int)(bs >> 11);
    long src = bs * QKV_W + 2048 + g * 128 + j;
    float x1 = bf2f(qkv[src]), x2 = bf2f(qkv[src + 64]);
    float c = cosT[s * 64 + j], sn = sinT[s * 64 + j];
    long dst = ((long)(b * NGROUPS + g) * S_LEN + s) * DHEAD + j;
    Kb[dst] = f2bf(x1 * c - x2 * sn);
    Kb[dst + 64] = f2bf(x2 * c + x1 * sn);
  } else {
    // V transpose: qkv cols [2560,3072) -> Vt (B,4,128,S)
    const int idx = bx - 4096;              // 64 x 4 x 8 = 2048 blocks
    const int s0 = (idx & 63) * 32;
    const int d0 = ((idx >> 6) & 3) * 32;
    const int bg = idx >> 8;
    const int b = bg >> 2, g = bg & 3;
    const int tx = threadIdx.x & 31, ty = threadIdx.x >> 5;   // (32,8)
    for (int i = 0; i < 32; i += 8) {
      long s = s0 + ty + i;
      tile[ty + i][tx] = qkv[((long)b * S_LEN + s) * QKV_W + 2560 + g * 128 + d0 + tx];
    }
    __syncthreads();
    for (int i = 0; i < 32; i += 8) {
      int d = d0 + ty + i;
      Vt[((long)(b * NGROUPS + g) * DHEAD + d) * S_LEN + s0 + tx] = tile[tx][ty + i];
    }
  }
}

// ---- Flash attention v13: key-split wave pairs, conflict-free P + scr ----
// (best measured attention: 69.2-69.7 us; unchanged this round)
__global__ __launch_bounds__(512, 2) void attn_k13(
    const u16* __restrict__ Q,   // qkv (B,S,3072), cols [0,2048) PRE-rope
    const u16* __restrict__ Kb,  // (B,4,S,128)  post-rope
    const u16* __restrict__ Vt,  // (B,4,128,S)
    const float* __restrict__ cosT, const float* __restrict__ sinT,
    u16* __restrict__ ctx) {     // (B,S,16,128)
  __shared__ __align__(16) char smem[82432];
  __bf16* Ks   = (__bf16*)smem;             // [2][64*128]  32 KB
  __bf16* Vts  = (__bf16*)(smem + 32768);   // [2][128*64]  32 KB
  __bf16* Ps   = (__bf16*)(smem + 65536);   // [4 rg][32*64] 16 KB
  float*  Psum = (float*)(smem + 81920);    // [128]        512 B
  float*  scr  = (float*)smem;              // epilogue overlay (66 KB @132)

  const int h = blockIdx.y, b = blockIdx.z, g = h >> 2;
  const int tx = blockIdx.x;                // 0..7
  const int tid = threadIdx.x, wv = tid >> 6, lane = tid & 63;
  const int quad = lane >> 4, l16 = lane & 15;
  const int rg = wv & 3;        // row-group within tile (32 rows)
  const int kh = wv >> 2;       // key half of each chunk
  const float SCALE = 0.08838834764831845f;

  const long kbase = (long)(b * NGROUPS + g) * S_LEN * DHEAD;
  const long vbase = (long)(b * NGROUPS + g) * DHEAD * S_LEN;

  const int krow_off = lane >> 4;
  const int vrow_off = lane >> 3;

  const __bf16 oneb = (__bf16)((l16 == 0) ? 1.0f : 0.0f);
  const bf16x8 bones = {oneb, oneb, oneb, oneb, oneb, oneb, oneb, oneb};

  __bf16* Prg = Ps + rg * 2048;  // row-group's 32x64 P tile (shared by pair)

  for (int pass = 0; pass < 2; ++pass) {
    const int tile = pass ? (15 - tx) : tx;
    const int q0 = tile * 128;
    const int nch = 2 * (tile + 1);   // 64-key chunks

    // Q fragments with fused RoPE: rows q0 + rg*32 + m*16 + l16
    bf16x8 aq[2][4];
#pragma unroll
    for (int m = 0; m < 2; ++m) {
      const int srow = q0 + rg * 32 + m * 16 + l16;
      const u16* qp = Q + (long)(b * S_LEN + srow) * QKV_W + h * DHEAD + quad * 8;
      bf16x8 raw[4];
#pragma unroll
      for (int ds = 0; ds < 4; ++ds)
        raw[ds] = *(const bf16x8*)(qp + ds * 32);
      const float* cb = cosT + srow * 64 + quad * 8;
      const float* sb = sinT + srow * 64 + quad * 8;
#pragma unroll
      for (int ds = 0; ds < 2; ++ds)
#pragma unroll
        for (int e = 0; e < 8; ++e) {
          float c = cb[ds * 32 + e], s = sb[ds * 32 + e];
          float lo = (float)raw[ds][e], hi = (float)raw[ds + 2][e];
          aq[m][ds][e]     = (__bf16)(lo * c - hi * s);
          aq[m][ds + 2][e] = (__bf16)(hi * c + lo * s);
        }
    }

    // prologue: stage K/V chunk 0 into buffer 0 (8 waves, 2 issues each)
#pragma unroll
    for (int i = 0; i < 2; ++i) {
      int r0 = wv * 8 + i * 4;
      int row = r0 + krow_off;
      int c = l16 ^ (row & 15);
      llds16(Kb + kbase + (long)row * DHEAD + c * 8, &Ks[r0 * 128 + lane * 8]);
    }
#pragma unroll
    for (int i = 0; i < 2; ++i) {
      int d0 = wv * 16 + i * 8;
      int row = d0 + vrow_off;
      int c = (lane & 7) ^ (row & 7);
      llds16(Vt + vbase + (long)row * S_LEN + c * 8, &Vts[d0 * 64 + lane * 8]);
    }
    __syncthreads();

    f32x4 Oacc[2][8] = {};
    f32x4 Osum[2] = {};
    const int rmin = q0 + rg * 32;   // wave's lowest q-row

    for (int kc = 0; kc < nch; ++kc) {
      const int cur = kc & 1;
      if (kc + 1 < nch) {
        const int nxt = cur ^ 1;
#pragma unroll
        for (int i = 0; i < 2; ++i) {
          int r0 = wv * 8 + i * 4;
          int row = r0 + krow_off;
          int c = l16 ^ (row & 15);
          llds16(Kb + kbase + (long)((kc + 1) * 64 + row) * DHEAD + c * 8,
                 &Ks[nxt * 8192 + r0 * 128 + lane * 8]);
        }
#pragma unroll
        for (int i = 0; i < 2; ++i) {
          int d0 = wv * 16 + i * 8;
          int row = d0 + vrow_off;
          int c = (lane & 7) ^ (row & 7);
          llds16(Vt + vbase + (long)row * S_LEN + (kc + 1) * 64 + c * 8,
                 &Vts[nxt * 8192 + d0 * 64 + lane * 8]);
        }
      }

      const int kb0 = kc * 64 + kh * 32;            // wave's key base
      const bool skip = kb0 > (rmin + 31);          // fully above diagonal
      if (!skip) {
        // QK^T: 32q x 32k per wave (16 MFMA, 8 K-frag reads)
        f32x4 sacc[2][2] = {};
        __builtin_amdgcn_s_setprio(1);
#pragma unroll
        for (int ds = 0; ds < 4; ++ds) {
          int pos0 = ((ds * 4 + quad) ^ l16) * 8;
#pragma unroll
          for (int nt = 0; nt < 2; ++nt) {
            bf16x8 bk = *(const bf16x8*)&Ks[cur * 8192 + (kh * 32 + nt * 16 + l16) * 128 + pos0];
            sacc[0][nt] = __builtin_amdgcn_mfma_f32_16x16x32_bf16(aq[0][ds], bk, sacc[0][nt], 0, 0, 0);
            sacc[1][nt] = __builtin_amdgcn_mfma_f32_16x16x32_bf16(aq[1][ds], bk, sacc[1][nt], 0, 0, 0);
          }
        }
        __builtin_amdgcn_s_setprio(0);

        // softmax -> P tile: granule gq = kh*4 + local, pos = gq ^ (row&7)
        const bool need_mask = (kb0 + 31) > rmin;
        if (need_mask) {
#pragma unroll
          for (int m = 0; m < 2; ++m)
#pragma unroll
            for (int nt = 0; nt < 2; ++nt)
#pragma unroll
              for (int r = 0; r < 4; ++r) {
                int qrow = rmin + m * 16 + quad * 4 + r;
                int key = kb0 + nt * 16 + l16;
                float p = (key <= qrow) ? __expf(sacc[m][nt][r] * SCALE) : 0.f;
                int row = m * 16 + quad * 4 + r;
                int gq = kh * 4 + nt * 2 + (l16 >> 3);
                int pos = gq ^ (row & 7);
                Prg[row * 64 + pos * 8 + (l16 & 7)] = (__bf16)p;
              }
        } else {
#pragma unroll
          for (int m = 0; m < 2; ++m)
#pragma unroll
            for (int nt = 0; nt < 2; ++nt)
#pragma unroll
              for (int r = 0; r < 4; ++r) {
                float p = __expf(sacc[m][nt][r] * SCALE);
                int row = m * 16 + quad * 4 + r;
                int gq = kh * 4 + nt * 2 + (l16 >> 3);
                int pos = gq ^ (row & 7);
                Prg[row * 64 + pos * 8 + (l16 & 7)] = (__bf16)p;
              }
        }

        // PV over wave's 32 keys (K=32: one MFMA step), 8 V-frag reads
        bf16x8 ap[2];
#pragma unroll
        for (int m = 0; m < 2; ++m) {
          int pos = (kh * 4 + quad) ^ (l16 & 7);
          ap[m] = *(const bf16x8*)&Prg[(m * 16 + l16) * 64 + pos * 8];
        }
        __builtin_amdgcn_s_setprio(1);
#pragma unroll
        for (int nt = 0; nt < 8; ++nt) {
          int pos = (((kh << 2) | quad) ^ (l16 & 7)) * 8;
          bf16x8 bv = *(const bf16x8*)&Vts[cur * 8192 + (nt * 16 + l16) * 64 + pos];
          Oacc[0][nt] = __builtin_amdgcn_mfma_f32_16x16x32_bf16(ap[0], bv, Oacc[0][nt], 0, 0, 0);
          Oacc[1][nt] = __builtin_amdgcn_mfma_f32_16x16x32_bf16(ap[1], bv, Oacc[1][nt], 0, 0, 0);
        }
#pragma unroll
        for (int m = 0; m < 2; ++m)
          Osum[m] = __builtin_amdgcn_mfma_f32_16x16x32_bf16(ap[m], bones, Osum[m], 0, 0, 0);
        __builtin_amdgcn_s_setprio(0);
      }

      __syncthreads();
    }

    // ---- combine wave pair (kh=1 partial added into kh=0) ----
    if (kh == 1) {
      float* s = scr + rg * 4224;   // 32 rows x 132-stride f32 (2-way banks)
#pragma unroll
      for (int m = 0; m < 2; ++m)
#pragma unroll
        for (int nt = 0; nt < 8; ++nt)
#pragma unroll
          for (int r = 0; r < 4; ++r)
            s[(m * 16 + quad * 4 + r) * 132 + nt * 16 + l16] = Oacc[m][nt][r];
      if (l16 == 0) {
#pragma unroll
        for (int m = 0; m < 2; ++m)
#pragma unroll
          for (int r = 0; r < 4; ++r)
            Psum[rg * 32 + m * 16 + quad * 4 + r] = Osum[m][r];
      }
    }
    __syncthreads();
    if (kh == 0) {
      float* s = scr + rg * 4224;
#pragma unroll
      for (int m = 0; m < 2; ++m) {
        float lsum[4];
#pragma unroll
        for (int r = 0; r < 4; ++r)
          lsum[r] = __shfl(Osum[m][r], quad << 4, 64) +
                    Psum[rg * 32 + m * 16 + quad * 4 + r];
        const long obase = ((long)(b * S_LEN + q0 + rg * 32 + m * 16) * NHEADS + h) * DHEAD;
#pragma unroll
        for (int nt = 0; nt < 8; ++nt)
#pragma unroll
          for (int r = 0; r < 4; ++r) {
            int lrow = quad * 4 + r;
            float v = Oacc[m][nt][r] + s[(m * 16 + lrow) * 132 + nt * 16 + l16];
            ctx[obase + (long)lrow * NHEADS * DHEAD + nt * 16 + l16] = f2bf(v / lsum[r]);
          }
      }
    }
    __syncthreads();   // scratch free before next pass restages K/V
  }
}

extern "C" void kernel_launch(void* const* d_in, const int* in_sizes, int n_in,
                              void* d_out, int out_size, void* d_ws, size_t ws_size,
                              hipStream_t stream) {
  const float* x   = (const float*)d_in[0];   // (B,S,2048) fp32
  const float* wq  = (const float*)d_in[1];   // (2048, 2048) fp32
  const float* wkv = (const float*)d_in[2];   // (2048, 1024) fp32
  const float* wd  = (const float*)d_in[3];   // (2048, 2048) fp32
  float* out = (float*)d_out;                 // (B,S,2048) fp32

  char* ws = (char*)d_ws;
  float* cosT  = (float*)(ws + 0);             //   524288 B
  float* sinT  = (float*)(ws + 524288);        //   524288 B
  u16* wqkvT = (u16*)(ws + 1048576);           // 12582912 B (3072 x 2048 bf16)
  u16* wdT   = (u16*)(ws + 13631488);          //  8388608 B (2048 x 2048 bf16)
  u16* xb    = (u16*)(ws + 22020096);          // 16777216 B (B*S, 2048) bf16
  u16* qkv   = (u16*)(ws + 38797312);          // 25165824 B (B*S, 3072) bf16
  u16* Kb    = (u16*)(ws + 63963136);          //  4194304 B (B,4,S,128) bf16
  u16* Vt    = (u16*)(ws + 68157440);          //  4194304 B (B,4,128,S) bf16
  u16* ctx   = (u16*)(ws + 72351744);          // 16777216 B (B,S,16,128) bf16
                                               // total 89128960 B

  rope_tables_k<<<512, 256, 0, stream>>>(cosT, sinT);
  cvt_f32_bf16<<<8192, 256, 0, stream>>>(x, xb);
  transpose3_k<<<dim3(64, 64, 3), dim3(32, 8), 0, stream>>>(wq, wkv, wd, wqkvT, wdT);

  // fused QKV projection: (B*S,2048) x (3072,2048)^T -> (B*S,3072)
  gemm_btw<<<dim3(16, 16), 512, 0, stream>>>(xb, wqkvT, qkv, 4096, 3072, 2048);

  // merged RoPE-K + V-transpose
  kv_prep_k<<<6144, 256, 0, stream>>>(qkv, Kb, Vt, cosT, sinT);

  attn_k13<<<dim3(8, 16, 2), 512, 0, stream>>>(qkv, Kb, Vt, cosT, sinT, ctx);

  // dense out: (B*S,2048) x (2048,2048)^T -> (B*S,2048), 2-phase, 256 blocks
  gemm_bt8n<<<dim3(16, 16), 512, 0, stream>>>(ctx, wdT, out, 4096, 2048, 2048);
}